// Round 1
// baseline (9984.808 us; speedup 1.0000x reference)
//
#include <hip/hip_runtime.h>
#include <math.h>

#define NS 1000
#define NQ 131072
#define D  1024
#define C  100
#define CP 112          // padded class count (16*7)
#define BETA 5.0f
#define NITER 10
#define KB 8
#define KC 64           // split-K chunks for w^T q
#define KROWS (NQ/KC)   // 2048

// ---------------- small prep kernels ----------------

__global__ __launch_bounds__(256) void k_mean(const float* __restrict__ sx,
                                              float* __restrict__ mean) {
  int d = blockIdx.x * 256 + threadIdx.x;
  float a = 0.f;
  for (int r = 0; r < NS; ++r) a += sx[(size_t)r * D + d];
  mean[d] = a / (float)NS;
}

// one block per row: inv L2 norm of (x - mean)
__global__ __launch_bounds__(256) void k_invn(const float* __restrict__ x,
                                              const float* __restrict__ mean,
                                              float* __restrict__ invn) {
  int r = blockIdx.x;
  int t = threadIdx.x;
  float4 v = ((const float4*)(x + (size_t)r * D))[t];
  float4 m = ((const float4*)mean)[t];
  float a = v.x - m.x, b = v.y - m.y, c = v.z - m.z, d = v.w - m.w;
  float s = a * a + b * b + c * c + d * d;
#pragma unroll
  for (int off = 1; off < 64; off <<= 1) s += __shfl_xor(s, off);
  __shared__ float ws[4];
  if ((t & 63) == 0) ws[t >> 6] = s;
  __syncthreads();
  if (t == 0) invn[r] = 1.0f / sqrtf(ws[0] + ws[1] + ws[2] + ws[3]);
}

// per-class support sums (normalized rows) + counts; pad classes -> zeros
__global__ __launch_bounds__(256) void k_supsum(const float* __restrict__ sx,
        const int* __restrict__ sy, const float* __restrict__ mean,
        const float* __restrict__ invs, float* __restrict__ supsum,
        float* __restrict__ supcnt) {
  int c = blockIdx.x;
  int t = threadIdx.x;
  float a0 = 0.f, a1 = 0.f, a2 = 0.f, a3 = 0.f;
  int cnt = 0;
  if (c < C) {
    for (int r = 0; r < NS; ++r) {
      if (sy[r] == c) {
        ++cnt;
        float inv = invs[r];
        a0 += (sx[(size_t)r * D + t      ] - mean[t      ]) * inv;
        a1 += (sx[(size_t)r * D + t + 256] - mean[t + 256]) * inv;
        a2 += (sx[(size_t)r * D + t + 512] - mean[t + 512]) * inv;
        a3 += (sx[(size_t)r * D + t + 768] - mean[t + 768]) * inv;
      }
    }
  }
  supsum[(size_t)c * D + t      ] = a0;
  supsum[(size_t)c * D + t + 256] = a1;
  supsum[(size_t)c * D + t + 512] = a2;
  supsum[(size_t)c * D + t + 768] = a3;
  if (t == 0) supcnt[c] = (float)cnt;
}

__global__ __launch_bounds__(256) void k_cent0(const float* __restrict__ supsum,
        const float* __restrict__ supcnt, float* __restrict__ cent) {
  int c = blockIdx.x;
  int d = blockIdx.y * 256 + threadIdx.x;
  float cnt = supcnt[c];
  cent[(size_t)c * D + d] = (c < C) ? supsum[(size_t)c * D + d] / cnt : 0.0f;
}

// squared norm per centroid row; pads get +1e30 so their logit is -inf
__global__ __launch_bounds__(256) void k_c2(const float* __restrict__ cent,
                                            float* __restrict__ c2) {
  int c = blockIdx.x;
  int t = threadIdx.x;
  float4 v = ((const float4*)(cent + (size_t)c * D))[t];
  float s = v.x * v.x + v.y * v.y + v.z * v.z + v.w * v.w;
#pragma unroll
  for (int off = 1; off < 64; off <<= 1) s += __shfl_xor(s, off);
  __shared__ float ws[4];
  if ((t & 63) == 0) ws[t >> 6] = s;
  __syncthreads();
  if (t == 0) c2[c] = (c < C) ? (ws[0] + ws[1] + ws[2] + ws[3]) : 1e30f;
}

// ---------------- K1 / K4: q @ cent^T (+softmax -> W, or argmax -> count) ----------------

template<bool FINAL>
__global__ __launch_bounds__(256) void k_qc(const float* __restrict__ qx,
        const float* __restrict__ mean, const float* __restrict__ invq,
        const float* __restrict__ cent, const float* __restrict__ c2,
        float* __restrict__ W, const int* __restrict__ qy,
        int* __restrict__ corr) {
  __shared__ __align__(16) float As[KB][132];   // [k][m], 128 rows
  __shared__ __align__(16) float Bs[KB][116];   // [k][c], 112 classes
  __shared__ __align__(16) float means[D];
  __shared__ float invns[128];
  int t = threadIdx.x;
  int m0 = blockIdx.x * 128;
  for (int i = t; i < D / 4; i += 256) ((float4*)means)[i] = ((const float4*)mean)[i];
  if (t < 128) invns[t] = invq[m0 + t];
  __syncthreads();

  int tm = t >> 4, tn = t & 15;           // rows tm*8..+7, cols tn+16j (j<7)
  int ar = t >> 1, ak = (t & 1) * 4;      // A loader
  const float* aptr = qx + (size_t)(m0 + ar) * D + ak;
  float ainv = invns[ar];
  int bc = t >> 1, bk = (t & 1) * 4;      // B loader (t<224)
  const float* bptr = cent + (size_t)bc * D + bk;
  bool bact = (t < 224);

  float acc[8][7];
#pragma unroll
  for (int r = 0; r < 8; ++r)
#pragma unroll
    for (int j = 0; j < 7; ++j) acc[r][j] = 0.f;

  for (int k0 = 0; k0 < D; k0 += KB) {
    float4 av = *(const float4*)(aptr + k0);
    float4 bv = make_float4(0.f, 0.f, 0.f, 0.f);
    if (bact) bv = *(const float4*)(bptr + k0);
    __syncthreads();
    As[ak + 0][ar] = (av.x - means[k0 + ak + 0]) * ainv;
    As[ak + 1][ar] = (av.y - means[k0 + ak + 1]) * ainv;
    As[ak + 2][ar] = (av.z - means[k0 + ak + 2]) * ainv;
    As[ak + 3][ar] = (av.w - means[k0 + ak + 3]) * ainv;
    if (bact) {
      Bs[bk + 0][bc] = bv.x; Bs[bk + 1][bc] = bv.y;
      Bs[bk + 2][bc] = bv.z; Bs[bk + 3][bc] = bv.w;
    }
    __syncthreads();
#pragma unroll
    for (int k = 0; k < KB; ++k) {
      float a[8], b[7];
      *(float4*)&a[0] = *(const float4*)&As[k][tm * 8];
      *(float4*)&a[4] = *(const float4*)&As[k][tm * 8 + 4];
#pragma unroll
      for (int j = 0; j < 7; ++j) b[j] = Bs[k][tn + 16 * j];
#pragma unroll
      for (int r = 0; r < 8; ++r)
#pragma unroll
        for (int j = 0; j < 7; ++j) acc[r][j] = fmaf(a[r], b[j], acc[r][j]);
    }
  }

  float c2v[7];
#pragma unroll
  for (int j = 0; j < 7; ++j) c2v[j] = c2[tn + 16 * j];

  if (!FINAL) {
#pragma unroll
    for (int r = 0; r < 8; ++r) {
      float l[7];
#pragma unroll
      for (int j = 0; j < 7; ++j) l[j] = 2.0f * acc[r][j] - c2v[j];
      float mx = l[0];
#pragma unroll
      for (int j = 1; j < 7; ++j) mx = fmaxf(mx, l[j]);
#pragma unroll
      for (int off = 1; off < 16; off <<= 1) mx = fmaxf(mx, __shfl_xor(mx, off));
      float e[7], s = 0.f;
#pragma unroll
      for (int j = 0; j < 7; ++j) { e[j] = expf(BETA * (l[j] - mx)); s += e[j]; }
#pragma unroll
      for (int off = 1; off < 16; off <<= 1) s += __shfl_xor(s, off);
      float is = 1.0f / s;
      size_t row = (size_t)(m0 + tm * 8 + r) * CP;
#pragma unroll
      for (int j = 0; j < 7; ++j) W[row + tn + 16 * j] = e[j] * is;
    }
  } else {
    int cnt = 0;
#pragma unroll
    for (int r = 0; r < 8; ++r) {
      float bvv = -INFINITY; int bi = 0x7fffffff;
#pragma unroll
      for (int j = 0; j < 7; ++j) {
        float l = 2.0f * acc[r][j] - c2v[j];
        int cc = tn + 16 * j;
        if (l > bvv || (l == bvv && cc < bi)) { bvv = l; bi = cc; }
      }
#pragma unroll
      for (int off = 1; off < 16; off <<= 1) {
        float ov = __shfl_xor(bvv, off);
        int   oi = __shfl_xor(bi, off);
        if (ov > bvv || (ov == bvv && oi < bi)) { bvv = ov; bi = oi; }
      }
      if (tn == 0) cnt += (bi == qy[m0 + tm * 8 + r]) ? 1 : 0;
    }
    if (tn == 0) atomicAdd(corr, cnt);   // integer add: deterministic
  }
}

// ---------------- K2: partials of W^T @ q  (M=112 classes, N=128 dims, split-K) ----------------

__global__ __launch_bounds__(256) void k_wq(const float* __restrict__ W,
        const float* __restrict__ qx, const float* __restrict__ mean,
        const float* __restrict__ invq, float* __restrict__ part) {
  __shared__ __align__(16) float Ws[KB][116];
  __shared__ __align__(16) float Qs[KB][132];
  __shared__ __align__(16) float means[128];
  int t = threadIdx.x;
  int n0 = blockIdx.x * 128;
  int kbeg = blockIdx.y * KROWS;
  if (t < 32) ((float4*)means)[t] = ((const float4*)(mean + n0))[t];
  __syncthreads();

  int tm = t >> 4, tn = t & 15;        // classes tm+16j (j<7), dims tn*4+64i (+0..3)
  int wr = t / 28, wc = (t % 28) * 4;  // W loader (t<224)
  bool wact = (t < 224);
  int qr = t >> 5, qc = (t & 31) * 4;  // q loader

  float acc[7][8];
#pragma unroll
  for (int j = 0; j < 7; ++j)
#pragma unroll
    for (int x = 0; x < 8; ++x) acc[j][x] = 0.f;

  for (int k0 = 0; k0 < KROWS; k0 += KB) {
    float4 wv = make_float4(0.f, 0.f, 0.f, 0.f);
    if (wact) wv = *(const float4*)(W + (size_t)(kbeg + k0 + wr) * CP + wc);
    float4 qv = *(const float4*)(qx + (size_t)(kbeg + k0 + qr) * D + n0 + qc);
    float qi = invq[kbeg + k0 + qr];
    __syncthreads();
    if (wact) *(float4*)&Ws[wr][wc] = wv;
    *(float4*)&Qs[qr][qc] = make_float4((qv.x - means[qc + 0]) * qi,
                                        (qv.y - means[qc + 1]) * qi,
                                        (qv.z - means[qc + 2]) * qi,
                                        (qv.w - means[qc + 3]) * qi);
    __syncthreads();
#pragma unroll
    for (int k = 0; k < KB; ++k) {
      float a[7], b[8];
#pragma unroll
      for (int j = 0; j < 7; ++j) a[j] = Ws[k][tm + 16 * j];
      *(float4*)&b[0] = *(const float4*)&Qs[k][tn * 4];
      *(float4*)&b[4] = *(const float4*)&Qs[k][tn * 4 + 64];
#pragma unroll
      for (int j = 0; j < 7; ++j)
#pragma unroll
        for (int x = 0; x < 8; ++x) acc[j][x] = fmaf(a[j], b[x], acc[j][x]);
    }
  }
#pragma unroll
  for (int j = 0; j < 7; ++j) {
    size_t base = ((size_t)blockIdx.y * CP + tm + 16 * j) * D + n0;
    *(float4*)&part[base + tn * 4]      = make_float4(acc[j][0], acc[j][1], acc[j][2], acc[j][3]);
    *(float4*)&part[base + tn * 4 + 64] = make_float4(acc[j][4], acc[j][5], acc[j][6], acc[j][7]);
  }
}

// column sums of W over 256-row chunks (for sumb)
__global__ __launch_bounds__(128) void k_wsum(const float* __restrict__ W,
                                              float* __restrict__ wsump) {
  int b = blockIdx.x;
  int c = threadIdx.x;
  if (c >= CP) return;
  float s = 0.f;
  const float* p = W + (size_t)b * 256 * CP + c;
  for (int r = 0; r < 256; ++r) s += p[(size_t)r * CP];
  wsump[b * CP + c] = s;
}

__global__ __launch_bounds__(128) void k_sumb(const float* __restrict__ wsump,
        const float* __restrict__ supcnt, float* __restrict__ sumb) {
  int c = threadIdx.x;
  if (c >= CP) return;
  float s = supcnt[c];
  for (int b = 0; b < NQ / 256; ++b) s += wsump[b * CP + c];
  sumb[c] = s;
}

__global__ __launch_bounds__(256) void k_upd(const float* __restrict__ supsum,
        const float* __restrict__ part, const float* __restrict__ sumb,
        float* __restrict__ cent) {
  int c = blockIdx.x;
  int d = blockIdx.y * 256 + threadIdx.x;
  float s = supsum[(size_t)c * D + d];
  for (int kc = 0; kc < KC; ++kc) s += part[((size_t)kc * CP + c) * D + d];
  cent[(size_t)c * D + d] = (c < C) ? s / sumb[c] : 0.f;
}

__global__ void k_zero(int* __restrict__ corr) {
  if (threadIdx.x == 0) corr[0] = 0;
}

__global__ void k_out(const int* __restrict__ corr, float* __restrict__ out) {
  if (threadIdx.x == 0) out[0] = (float)corr[0] * (1.0f / (float)NQ);
}

// ---------------- launch ----------------

extern "C" void kernel_launch(void* const* d_in, const int* in_sizes, int n_in,
                              void* d_out, int out_size, void* d_ws, size_t ws_size,
                              hipStream_t stream) {
  const float* sx = (const float*)d_in[0];
  const int*   sy = (const int*)d_in[1];
  const float* qx = (const float*)d_in[2];
  const int*   qy = (const int*)d_in[3];

  float* ws = (float*)d_ws;
  float* mean   = ws;                       // 1024
  float* invs   = mean + 1024;              // 1024 (1000 used)
  float* supsum = invs + 1024;              // CP*D
  float* supcnt = supsum + (size_t)CP * D;  // 128
  float* cA     = supcnt + 128;             // CP*D
  float* cB     = cA + (size_t)CP * D;      // CP*D
  float* c2     = cB + (size_t)CP * D;      // 128
  float* invq   = c2 + 128;                 // NQ
  float* W      = invq + NQ;                // NQ*CP
  float* part   = W + (size_t)NQ * CP;      // KC*CP*D
  float* wsump  = part + (size_t)KC * CP * D; // (NQ/256)*CP
  float* sumb   = wsump + (size_t)(NQ / 256) * CP; // 128
  int*   corr   = (int*)(sumb + 128);       // 1 (pad 1024)
  size_t needed = (size_t)((sumb + 128 + 1024) - ws) * sizeof(float);
  if (ws_size < needed) {  // can't run: write a sentinel so failure is visible, no OOB
    k_zero<<<1, 64, 0, stream>>>((int*)d_out);
    return;
  }

  k_mean<<<dim3(D / 256), 256, 0, stream>>>(sx, mean);
  k_invn<<<dim3(NS), 256, 0, stream>>>(sx, mean, invs);
  k_invn<<<dim3(NQ), 256, 0, stream>>>(qx, mean, invq);
  k_supsum<<<dim3(CP), 256, 0, stream>>>(sx, sy, mean, invs, supsum, supcnt);
  k_cent0<<<dim3(CP, D / 256), 256, 0, stream>>>(supsum, supcnt, cA);
  k_c2<<<dim3(CP), 256, 0, stream>>>(cA, c2);

  float* cur = cA;
  float* nxt = cB;
  for (int it = 0; it < NITER; ++it) {
    k_qc<false><<<dim3(NQ / 128), 256, 0, stream>>>(qx, mean, invq, cur, c2, W, nullptr, nullptr);
    k_wsum<<<dim3(NQ / 256), 128, 0, stream>>>(W, wsump);
    k_sumb<<<dim3(1), 128, 0, stream>>>(wsump, supcnt, sumb);
    k_wq<<<dim3(D / 128, KC), 256, 0, stream>>>(W, qx, mean, invq, part);
    k_upd<<<dim3(CP, D / 256), 256, 0, stream>>>(supsum, part, sumb, nxt);
    k_c2<<<dim3(CP), 256, 0, stream>>>(nxt, c2);
    float* tmp = cur; cur = nxt; nxt = tmp;
  }

  k_zero<<<1, 64, 0, stream>>>(corr);
  k_qc<true><<<dim3(NQ / 128), 256, 0, stream>>>(qx, mean, invq, cur, c2, W, qy, corr);
  k_out<<<1, 64, 0, stream>>>(corr, (float*)d_out);
}

// Round 2
// 4450.246 us; speedup vs baseline: 2.2437x; 2.2437x over previous
//
#include <hip/hip_runtime.h>
#include <math.h>

#define NS 1000
#define NQ 131072
#define D  1024
#define C  100
#define CP 112          // padded class count (16*7)
#define BETA 5.0f
#define NITER 10
#define KB 8
#define KC 64           // split-K chunks for w^T q
#define KROWS (NQ/KC)   // 2048

typedef float f32x4 __attribute__((ext_vector_type(4)));
typedef short s16x8 __attribute__((ext_vector_type(8)));
typedef unsigned short u16;

__device__ __forceinline__ u16 f2bf(float x) {
  union { float f; unsigned u; } v; v.f = x;
  unsigned r = v.u + 0x7fffu + ((v.u >> 16) & 1u);
  return (u16)(r >> 16);
}
__device__ __forceinline__ float bf2f(u16 h) {
  union { unsigned u; float f; } v; v.u = ((unsigned)h) << 16; return v.f;
}
__device__ __forceinline__ void gld16(const u16* g, u16* l) {
  __builtin_amdgcn_global_load_lds(
      (const __attribute__((address_space(1))) void*)g,
      (__attribute__((address_space(3))) void*)l, 16, 0, 0);
}
__device__ __forceinline__ s16x8 ldsfrag(const u16* base, int row, int kb) {
  int s = kb ^ (row & 7);
  return *(const s16x8*)(base + row * 64 + s * 8);
}
__device__ __forceinline__ f32x4 mfma16(s16x8 a, s16x8 b, f32x4 c) {
  return __builtin_amdgcn_mfma_f32_16x16x32_bf16(a, b, c, 0, 0, 0);
}

// ---------------- shared prep kernels ----------------

__global__ __launch_bounds__(256) void k_mean(const float* __restrict__ sx,
                                              float* __restrict__ mean) {
  int d = blockIdx.x * 256 + threadIdx.x;
  float a = 0.f;
  for (int r = 0; r < NS; ++r) a += sx[(size_t)r * D + d];
  mean[d] = a / (float)NS;
}

__global__ __launch_bounds__(256) void k_invn(const float* __restrict__ x,
                                              const float* __restrict__ mean,
                                              float* __restrict__ invn) {
  int r = blockIdx.x;
  int t = threadIdx.x;
  float4 v = ((const float4*)(x + (size_t)r * D))[t];
  float4 m = ((const float4*)mean)[t];
  float a = v.x - m.x, b = v.y - m.y, c = v.z - m.z, d = v.w - m.w;
  float s = a * a + b * b + c * c + d * d;
#pragma unroll
  for (int off = 1; off < 64; off <<= 1) s += __shfl_xor(s, off);
  __shared__ float ws[4];
  if ((t & 63) == 0) ws[t >> 6] = s;
  __syncthreads();
  if (t == 0) invn[r] = 1.0f / sqrtf(ws[0] + ws[1] + ws[2] + ws[3]);
}

__global__ __launch_bounds__(256) void k_supsum(const float* __restrict__ sx,
        const int* __restrict__ sy, const float* __restrict__ mean,
        const float* __restrict__ invs, float* __restrict__ supsum,
        float* __restrict__ supcnt) {
  int c = blockIdx.x;
  int t = threadIdx.x;
  float a0 = 0.f, a1 = 0.f, a2 = 0.f, a3 = 0.f;
  int cnt = 0;
  if (c < C) {
    for (int r = 0; r < NS; ++r) {
      if (sy[r] == c) {
        ++cnt;
        float inv = invs[r];
        a0 += (sx[(size_t)r * D + t      ] - mean[t      ]) * inv;
        a1 += (sx[(size_t)r * D + t + 256] - mean[t + 256]) * inv;
        a2 += (sx[(size_t)r * D + t + 512] - mean[t + 512]) * inv;
        a3 += (sx[(size_t)r * D + t + 768] - mean[t + 768]) * inv;
      }
    }
  }
  supsum[(size_t)c * D + t      ] = a0;
  supsum[(size_t)c * D + t + 256] = a1;
  supsum[(size_t)c * D + t + 512] = a2;
  supsum[(size_t)c * D + t + 768] = a3;
  if (t == 0) supcnt[c] = (float)cnt;
}

__global__ void k_zero(int* __restrict__ corr) {
  if (threadIdx.x == 0) corr[0] = 0;
}

__global__ void k_out(const int* __restrict__ corr, float* __restrict__ out) {
  if (threadIdx.x == 0) out[0] = (float)corr[0] * (1.0f / (float)NQ);
}

// ---------------- fast path: bf16-split MFMA ----------------

// normalize q, split to bf16 hi/lo, write [q][d] and transposed [d][q] planes
__global__ __launch_bounds__(256) void k_qsplit(const float* __restrict__ qx,
        const float* __restrict__ mean, const float* __restrict__ invq,
        u16* __restrict__ qhi, u16* __restrict__ qlo,
        u16* __restrict__ qthi, u16* __restrict__ qtlo) {
  __shared__ u16 Lh[64][70], Ll[64][70];
  __shared__ float mloc[64], iloc[64];
  int t = threadIdx.x;
  int q0 = blockIdx.x * 64, d0 = blockIdx.y * 64;
  if (t < 64) mloc[t] = mean[d0 + t];
  else if (t < 128) iloc[t - 64] = invq[q0 + (t - 64)];
  __syncthreads();
  int r = t >> 2, c0 = (t & 3) * 16;
  float inv = iloc[r];
  const float* src = qx + (size_t)(q0 + r) * D + d0 + c0;
  u16 hb[16], lb[16];
#pragma unroll
  for (int j = 0; j < 16; j += 4) {
    float4 v = *(const float4*)(src + j);
    float xs[4] = {v.x, v.y, v.z, v.w};
#pragma unroll
    for (int u = 0; u < 4; ++u) {
      float x = (xs[u] - mloc[c0 + j + u]) * inv;
      u16 h = f2bf(x);
      u16 lo = f2bf(x - bf2f(h));
      hb[j + u] = h; lb[j + u] = lo;
      Lh[r][c0 + j + u] = h; Ll[r][c0 + j + u] = lo;
    }
  }
  u16* dh = qhi + (size_t)(q0 + r) * D + d0 + c0;
  u16* dl = qlo + (size_t)(q0 + r) * D + d0 + c0;
#pragma unroll
  for (int j = 0; j < 16; j += 4) {
    ushort4 uh, ul;
    uh.x = hb[j]; uh.y = hb[j + 1]; uh.z = hb[j + 2]; uh.w = hb[j + 3];
    ul.x = lb[j]; ul.y = lb[j + 1]; ul.z = lb[j + 2]; ul.w = lb[j + 3];
    *(ushort4*)(dh + j) = uh;
    *(ushort4*)(dl + j) = ul;
  }
  __syncthreads();
  int dd = t >> 2, qc = (t & 3) * 16;
  u16* th2 = qthi + (size_t)(d0 + dd) * NQ + q0 + qc;
  u16* tl2 = qtlo + (size_t)(d0 + dd) * NQ + q0 + qc;
#pragma unroll
  for (int j = 0; j < 16; j += 4) {
    ushort4 uh, ul;
    uh.x = Lh[qc + j][dd]; uh.y = Lh[qc + j + 1][dd];
    uh.z = Lh[qc + j + 2][dd]; uh.w = Lh[qc + j + 3][dd];
    ul.x = Ll[qc + j][dd]; ul.y = Ll[qc + j + 1][dd];
    ul.z = Ll[qc + j + 2][dd]; ul.w = Ll[qc + j + 3][dd];
    *(ushort4*)(th2 + j) = uh;
    *(ushort4*)(tl2 + j) = ul;
  }
}

// update centroids (or init with nparts=0), emit bf16 hi/lo planes + |c|^2
__global__ __launch_bounds__(256) void k_updm(const float* __restrict__ supsum,
        const float* __restrict__ part, const float* __restrict__ denom,
        u16* __restrict__ chi, u16* __restrict__ clo, float* __restrict__ c2,
        int nparts) {
  int c = blockIdx.x, t = threadIdx.x;
  float den = denom[c];
  float ss = 0.f;
  float vals[4];
#pragma unroll
  for (int j = 0; j < 4; ++j) {
    int d = t + j * 256;
    float s = supsum[(size_t)c * D + d];
    for (int kc = 0; kc < nparts; ++kc) s += part[((size_t)kc * CP + c) * D + d];
    float v = (c < C) ? s / den : 0.f;
    vals[j] = v; ss += v * v;
  }
#pragma unroll
  for (int j = 0; j < 4; ++j) {
    int d = t + j * 256;
    u16 h = f2bf(vals[j]);
    chi[(size_t)c * D + d] = h;
    clo[(size_t)c * D + d] = f2bf(vals[j] - bf2f(h));
  }
#pragma unroll
  for (int off = 1; off < 64; off <<= 1) ss += __shfl_xor(ss, off);
  __shared__ float red[4];
  if ((t & 63) == 0) red[t >> 6] = ss;
  __syncthreads();
  if (t == 0) c2[c] = (c < C) ? (red[0] + red[1] + red[2] + red[3]) : 1e30f;
}

// GEMM1: logits = 2*(qn @ cent^T) - c2 ; softmax -> Wt (bf16 hi/lo) + col sums
// or (final_) argmax -> correct count
__global__ __launch_bounds__(256) void k_logits(
    const u16* __restrict__ qhi, const u16* __restrict__ qlo,
    const u16* __restrict__ chi, const u16* __restrict__ clo,
    const float* __restrict__ c2,
    u16* __restrict__ Wthi, u16* __restrict__ Wtlo,
    float* __restrict__ wsump,
    const int* __restrict__ qy, int* __restrict__ corr, int final_) {
  __shared__ __align__(16) u16 sm[30720];
  __shared__ float wred[4][CP];
  u16 *Ahi = sm, *Alo = sm + 8192, *Bhi = sm + 16384, *Blo = sm + 23552;
  int t = threadIdx.x, w = t >> 6, l = t & 63;
  int q0 = blockIdx.x * 128;
  int sr = l >> 3, ss = l & 7;
  int swz = (ss ^ sr) << 3;

  f32x4 zero = {0.f, 0.f, 0.f, 0.f};
  f32x4 acc[2][7];
#pragma unroll
  for (int mf = 0; mf < 2; ++mf)
#pragma unroll
    for (int nf = 0; nf < 7; ++nf) acc[mf][nf] = zero;

  for (int ks = 0; ks < 16; ++ks) {
    int k0 = ks * 64;
    __syncthreads();
#pragma unroll
    for (int i = 0; i < 4; ++i) {
      int r = w * 32 + i * 8 + sr;
      gld16(qhi + (size_t)(q0 + r) * D + k0 + swz, Ahi + (w * 32 + i * 8) * 64);
      gld16(qlo + (size_t)(q0 + r) * D + k0 + swz, Alo + (w * 32 + i * 8) * 64);
    }
    for (int i = w; i < 14; i += 4) {
      int r = i * 8 + sr;
      gld16(chi + (size_t)r * D + k0 + swz, Bhi + i * 512);
      gld16(clo + (size_t)r * D + k0 + swz, Blo + i * 512);
    }
    asm volatile("s_waitcnt vmcnt(0)" ::: "memory");
    __syncthreads();
#pragma unroll
    for (int kh = 0; kh < 2; ++kh) {
      int kb = kh * 4 + (l >> 4);
      s16x8 ah[2], al[2], bh[7], bl[7];
#pragma unroll
      for (int mf = 0; mf < 2; ++mf) {
        int r = w * 32 + mf * 16 + (l & 15);
        ah[mf] = ldsfrag(Ahi, r, kb);
        al[mf] = ldsfrag(Alo, r, kb);
      }
#pragma unroll
      for (int nf = 0; nf < 7; ++nf) {
        int r = nf * 16 + (l & 15);
        bh[nf] = ldsfrag(Bhi, r, kb);
        bl[nf] = ldsfrag(Blo, r, kb);
      }
#pragma unroll
      for (int mf = 0; mf < 2; ++mf)
#pragma unroll
        for (int nf = 0; nf < 7; ++nf) {
          f32x4 a = acc[mf][nf];
          a = mfma16(ah[mf], bh[nf], a);
          a = mfma16(ah[mf], bl[nf], a);
          a = mfma16(al[mf], bh[nf], a);
          a = mfma16(al[mf], bl[nf], a);
          acc[mf][nf] = a;
        }
    }
  }
  __syncthreads();

  float c2v[7];
#pragma unroll
  for (int nf = 0; nf < 7; ++nf) c2v[nf] = c2[nf * 16 + (l & 15)];

  if (!final_) {
    float wcol[7];
#pragma unroll
    for (int nf = 0; nf < 7; ++nf) wcol[nf] = 0.f;
    u16* Wsh = sm;           // [112][128], column-swizzled
    u16* Wsl = sm + 14336;
#pragma unroll
    for (int mf = 0; mf < 2; ++mf)
#pragma unroll
      for (int r = 0; r < 4; ++r) {
        float L[7], mx = -INFINITY;
#pragma unroll
        for (int nf = 0; nf < 7; ++nf) {
          L[nf] = 2.f * acc[mf][nf][r] - c2v[nf];
          mx = fmaxf(mx, L[nf]);
        }
#pragma unroll
        for (int off = 1; off < 16; off <<= 1) mx = fmaxf(mx, __shfl_xor(mx, off));
        float e[7], s = 0.f;
#pragma unroll
        for (int nf = 0; nf < 7; ++nf) { e[nf] = expf(BETA * (L[nf] - mx)); s += e[nf]; }
#pragma unroll
        for (int off = 1; off < 16; off <<= 1) s += __shfl_xor(s, off);
        float is = 1.f / s;
        int qi = w * 32 + mf * 16 + (l >> 4) * 4 + r;
        int qs = qi ^ ((l & 15) << 3);   // bank-spread columns
#pragma unroll
        for (int nf = 0; nf < 7; ++nf) {
          float wv = e[nf] * is;
          wcol[nf] += wv;
          u16 h = f2bf(wv);
          Wsh[(nf * 16 + (l & 15)) * 128 + qs] = h;
          Wsl[(nf * 16 + (l & 15)) * 128 + qs] = f2bf(wv - bf2f(h));
        }
      }
#pragma unroll
    for (int off = 16; off < 64; off <<= 1)
#pragma unroll
      for (int nf = 0; nf < 7; ++nf) wcol[nf] += __shfl_xor(wcol[nf], off);
    if (l < 16)
#pragma unroll
      for (int nf = 0; nf < 7; ++nf) wred[w][nf * 16 + l] = wcol[nf];
    __syncthreads();
    for (int idx = t; idx < 1792; idx += 256) {
      int c = idx >> 4, p = idx & 15;
      int ps = p ^ (c & 15);
      *(uint4*)(Wthi + (size_t)c * NQ + q0 + p * 8) = *(const uint4*)(Wsh + c * 128 + ps * 8);
      *(uint4*)(Wtlo + (size_t)c * NQ + q0 + p * 8) = *(const uint4*)(Wsl + c * 128 + ps * 8);
    }
    if (t < CP) wsump[(size_t)blockIdx.x * CP + t] =
        wred[0][t] + wred[1][t] + wred[2][t] + wred[3][t];
  } else {
    int cnt = 0;
#pragma unroll
    for (int mf = 0; mf < 2; ++mf)
#pragma unroll
      for (int r = 0; r < 4; ++r) {
        float bv = -INFINITY; int bi = 0x7fffffff;
#pragma unroll
        for (int nf = 0; nf < 7; ++nf) {
          float L = 2.f * acc[mf][nf][r] - c2v[nf];
          int cc = nf * 16 + (l & 15);
          if (L > bv || (L == bv && cc < bi)) { bv = L; bi = cc; }
        }
#pragma unroll
        for (int off = 1; off < 16; off <<= 1) {
          float ov = __shfl_xor(bv, off); int oi = __shfl_xor(bi, off);
          if (ov > bv || (ov == bv && oi < bi)) { bv = ov; bi = oi; }
        }
        if ((l & 15) == 0) {
          int qi = w * 32 + mf * 16 + (l >> 4) * 4 + r;
          cnt += (bi == qy[q0 + qi]) ? 1 : 0;
        }
      }
    if ((l & 15) == 0) atomicAdd(corr, cnt);
  }
}

// GEMM2: part[ck] = Wt[:, chunk] @ qn[chunk, :]  (M=112, N=128/dtile, K=2048)
__global__ __launch_bounds__(256) void k_wqm(
    const u16* __restrict__ Wthi, const u16* __restrict__ Wtlo,
    const u16* __restrict__ qthi, const u16* __restrict__ qtlo,
    float* __restrict__ part) {
  __shared__ __align__(16) u16 sm[30720];
  u16 *AWh = sm, *AWl = sm + 7168, *QBh = sm + 14336, *QBl = sm + 22528;
  int t = threadIdx.x, w = t >> 6, l = t & 63;
  int d0 = blockIdx.x * 128;
  int ck = blockIdx.y;
  int sr = l >> 3, ss = l & 7;
  int swz = (ss ^ sr) << 3;

  f32x4 zero = {0.f, 0.f, 0.f, 0.f};
  f32x4 acc[7][2];
#pragma unroll
  for (int mf = 0; mf < 7; ++mf)
#pragma unroll
    for (int nf = 0; nf < 2; ++nf) acc[mf][nf] = zero;

  for (int ks = 0; ks < 32; ++ks) {
    size_t qk = (size_t)ck * KROWS + (size_t)ks * 64;
    __syncthreads();
    for (int i = w; i < 14; i += 4) {
      int r = i * 8 + sr;
      gld16(Wthi + (size_t)r * NQ + qk + swz, AWh + i * 512);
      gld16(Wtlo + (size_t)r * NQ + qk + swz, AWl + i * 512);
    }
#pragma unroll
    for (int i = 0; i < 4; ++i) {
      int r = w * 32 + i * 8 + sr;
      gld16(qthi + (size_t)(d0 + r) * NQ + qk + swz, QBh + (w * 32 + i * 8) * 64);
      gld16(qtlo + (size_t)(d0 + r) * NQ + qk + swz, QBl + (w * 32 + i * 8) * 64);
    }
    asm volatile("s_waitcnt vmcnt(0)" ::: "memory");
    __syncthreads();
#pragma unroll
    for (int kh = 0; kh < 2; ++kh) {
      int kb = kh * 4 + (l >> 4);
      s16x8 awh[7], awl[7], bqh[2], bql[2];
#pragma unroll
      for (int mf = 0; mf < 7; ++mf) {
        int r = mf * 16 + (l & 15);
        awh[mf] = ldsfrag(AWh, r, kb);
        awl[mf] = ldsfrag(AWl, r, kb);
      }
#pragma unroll
      for (int nf = 0; nf < 2; ++nf) {
        int r = w * 32 + nf * 16 + (l & 15);
        bqh[nf] = ldsfrag(QBh, r, kb);
        bql[nf] = ldsfrag(QBl, r, kb);
      }
#pragma unroll
      for (int mf = 0; mf < 7; ++mf)
#pragma unroll
        for (int nf = 0; nf < 2; ++nf) {
          f32x4 a = acc[mf][nf];
          a = mfma16(awh[mf], bqh[nf], a);
          a = mfma16(awh[mf], bql[nf], a);
          a = mfma16(awl[mf], bqh[nf], a);
          a = mfma16(awl[mf], bql[nf], a);
          acc[mf][nf] = a;
        }
    }
  }
#pragma unroll
  for (int mf = 0; mf < 7; ++mf)
#pragma unroll
    for (int nf = 0; nf < 2; ++nf)
#pragma unroll
      for (int r = 0; r < 4; ++r) {
        int c = mf * 16 + (l >> 4) * 4 + r;
        int dg = d0 + w * 32 + nf * 16 + (l & 15);
        part[((size_t)ck * CP + c) * D + dg] = acc[mf][nf][r];
      }
}

__global__ __launch_bounds__(128) void k_sumbm(const float* __restrict__ wsump,
        const float* __restrict__ supcnt, float* __restrict__ sumb) {
  int c = threadIdx.x;
  if (c >= CP) return;
  float s = supcnt[c];
  for (int b = 0; b < NQ / 128; ++b) s += wsump[(size_t)b * CP + c];
  sumb[c] = s;
}

// ---------------- fallback path (round-1, proven) ----------------

__global__ __launch_bounds__(256) void k_cent0(const float* __restrict__ supsum,
        const float* __restrict__ supcnt, float* __restrict__ cent) {
  int c = blockIdx.x;
  int d = blockIdx.y * 256 + threadIdx.x;
  float cnt = supcnt[c];
  cent[(size_t)c * D + d] = (c < C) ? supsum[(size_t)c * D + d] / cnt : 0.0f;
}

__global__ __launch_bounds__(256) void k_c2(const float* __restrict__ cent,
                                            float* __restrict__ c2) {
  int c = blockIdx.x;
  int t = threadIdx.x;
  float4 v = ((const float4*)(cent + (size_t)c * D))[t];
  float s = v.x * v.x + v.y * v.y + v.z * v.z + v.w * v.w;
#pragma unroll
  for (int off = 1; off < 64; off <<= 1) s += __shfl_xor(s, off);
  __shared__ float ws[4];
  if ((t & 63) == 0) ws[t >> 6] = s;
  __syncthreads();
  if (t == 0) c2[c] = (c < C) ? (ws[0] + ws[1] + ws[2] + ws[3]) : 1e30f;
}

template<bool FINAL>
__global__ __launch_bounds__(256) void k_qc(const float* __restrict__ qx,
        const float* __restrict__ mean, const float* __restrict__ invq,
        const float* __restrict__ cent, const float* __restrict__ c2,
        float* __restrict__ W, const int* __restrict__ qy,
        int* __restrict__ corr) {
  __shared__ __align__(16) float As[KB][132];
  __shared__ __align__(16) float Bs[KB][116];
  __shared__ __align__(16) float means[D];
  __shared__ float invns[128];
  int t = threadIdx.x;
  int m0 = blockIdx.x * 128;
  for (int i = t; i < D / 4; i += 256) ((float4*)means)[i] = ((const float4*)mean)[i];
  if (t < 128) invns[t] = invq[m0 + t];
  __syncthreads();

  int tm = t >> 4, tn = t & 15;
  int ar = t >> 1, ak = (t & 1) * 4;
  const float* aptr = qx + (size_t)(m0 + ar) * D + ak;
  float ainv = invns[ar];
  int bc = t >> 1, bk = (t & 1) * 4;
  const float* bptr = cent + (size_t)bc * D + bk;
  bool bact = (t < 224);

  float acc[8][7];
#pragma unroll
  for (int r = 0; r < 8; ++r)
#pragma unroll
    for (int j = 0; j < 7; ++j) acc[r][j] = 0.f;

  for (int k0 = 0; k0 < D; k0 += KB) {
    float4 av = *(const float4*)(aptr + k0);
    float4 bv = make_float4(0.f, 0.f, 0.f, 0.f);
    if (bact) bv = *(const float4*)(bptr + k0);
    __syncthreads();
    As[ak + 0][ar] = (av.x - means[k0 + ak + 0]) * ainv;
    As[ak + 1][ar] = (av.y - means[k0 + ak + 1]) * ainv;
    As[ak + 2][ar] = (av.z - means[k0 + ak + 2]) * ainv;
    As[ak + 3][ar] = (av.w - means[k0 + ak + 3]) * ainv;
    if (bact) {
      Bs[bk + 0][bc] = bv.x; Bs[bk + 1][bc] = bv.y;
      Bs[bk + 2][bc] = bv.z; Bs[bk + 3][bc] = bv.w;
    }
    __syncthreads();
#pragma unroll
    for (int k = 0; k < KB; ++k) {
      float a[8], b[7];
      *(float4*)&a[0] = *(const float4*)&As[k][tm * 8];
      *(float4*)&a[4] = *(const float4*)&As[k][tm * 8 + 4];
#pragma unroll
      for (int j = 0; j < 7; ++j) b[j] = Bs[k][tn + 16 * j];
#pragma unroll
      for (int r = 0; r < 8; ++r)
#pragma unroll
        for (int j = 0; j < 7; ++j) acc[r][j] = fmaf(a[r], b[j], acc[r][j]);
    }
  }

  float c2v[7];
#pragma unroll
  for (int j = 0; j < 7; ++j) c2v[j] = c2[tn + 16 * j];

  if (!FINAL) {
#pragma unroll
    for (int r = 0; r < 8; ++r) {
      float l[7];
#pragma unroll
      for (int j = 0; j < 7; ++j) l[j] = 2.0f * acc[r][j] - c2v[j];
      float mx = l[0];
#pragma unroll
      for (int j = 1; j < 7; ++j) mx = fmaxf(mx, l[j]);
#pragma unroll
      for (int off = 1; off < 16; off <<= 1) mx = fmaxf(mx, __shfl_xor(mx, off));
      float e[7], s = 0.f;
#pragma unroll
      for (int j = 0; j < 7; ++j) { e[j] = expf(BETA * (l[j] - mx)); s += e[j]; }
#pragma unroll
      for (int off = 1; off < 16; off <<= 1) s += __shfl_xor(s, off);
      float is = 1.0f / s;
      size_t row = (size_t)(m0 + tm * 8 + r) * CP;
#pragma unroll
      for (int j = 0; j < 7; ++j) W[row + tn + 16 * j] = e[j] * is;
    }
  } else {
    int cnt = 0;
#pragma unroll
    for (int r = 0; r < 8; ++r) {
      float bvv = -INFINITY; int bi = 0x7fffffff;
#pragma unroll
      for (int j = 0; j < 7; ++j) {
        float l = 2.0f * acc[r][j] - c2v[j];
        int cc = tn + 16 * j;
        if (l > bvv || (l == bvv && cc < bi)) { bvv = l; bi = cc; }
      }
#pragma unroll
      for (int off = 1; off < 16; off <<= 1) {
        float ov = __shfl_xor(bvv, off);
        int   oi = __shfl_xor(bi, off);
        if (ov > bvv || (ov == bvv && oi < bi)) { bvv = ov; bi = oi; }
      }
      if (tn == 0) cnt += (bi == qy[m0 + tm * 8 + r]) ? 1 : 0;
    }
    if (tn == 0) atomicAdd(corr, cnt);
  }
}

__global__ __launch_bounds__(256) void k_wq(const float* __restrict__ W,
        const float* __restrict__ qx, const float* __restrict__ mean,
        const float* __restrict__ invq, float* __restrict__ part) {
  __shared__ __align__(16) float Ws[KB][116];
  __shared__ __align__(16) float Qs[KB][132];
  __shared__ __align__(16) float means[128];
  int t = threadIdx.x;
  int n0 = blockIdx.x * 128;
  int kbeg = blockIdx.y * KROWS;
  if (t < 32) ((float4*)means)[t] = ((const float4*)(mean + n0))[t];
  __syncthreads();

  int tm = t >> 4, tn = t & 15;
  int wr = t / 28, wc = (t % 28) * 4;
  bool wact = (t < 224);
  int qr = t >> 5, qc = (t & 31) * 4;

  float acc[7][8];
#pragma unroll
  for (int j = 0; j < 7; ++j)
#pragma unroll
    for (int x = 0; x < 8; ++x) acc[j][x] = 0.f;

  for (int k0 = 0; k0 < KROWS; k0 += KB) {
    float4 wv = make_float4(0.f, 0.f, 0.f, 0.f);
    if (wact) wv = *(const float4*)(W + (size_t)(kbeg + k0 + wr) * CP + wc);
    float4 qv = *(const float4*)(qx + (size_t)(kbeg + k0 + qr) * D + n0 + qc);
    float qi = invq[kbeg + k0 + qr];
    __syncthreads();
    if (wact) *(float4*)&Ws[wr][wc] = wv;
    *(float4*)&Qs[qr][qc] = make_float4((qv.x - means[qc + 0]) * qi,
                                        (qv.y - means[qc + 1]) * qi,
                                        (qv.z - means[qc + 2]) * qi,
                                        (qv.w - means[qc + 3]) * qi);
    __syncthreads();
#pragma unroll
    for (int k = 0; k < KB; ++k) {
      float a[7], b[8];
#pragma unroll
      for (int j = 0; j < 7; ++j) a[j] = Ws[k][tm + 16 * j];
      *(float4*)&b[0] = *(const float4*)&Qs[k][tn * 4];
      *(float4*)&b[4] = *(const float4*)&Qs[k][tn * 4 + 64];
#pragma unroll
      for (int j = 0; j < 7; ++j)
#pragma unroll
        for (int x = 0; x < 8; ++x) acc[j][x] = fmaf(a[j], b[x], acc[j][x]);
    }
  }
#pragma unroll
  for (int j = 0; j < 7; ++j) {
    size_t base = ((size_t)blockIdx.y * CP + tm + 16 * j) * D + n0;
    *(float4*)&part[base + tn * 4]      = make_float4(acc[j][0], acc[j][1], acc[j][2], acc[j][3]);
    *(float4*)&part[base + tn * 4 + 64] = make_float4(acc[j][4], acc[j][5], acc[j][6], acc[j][7]);
  }
}

__global__ __launch_bounds__(128) void k_wsum(const float* __restrict__ W,
                                              float* __restrict__ wsump) {
  int b = blockIdx.x;
  int c = threadIdx.x;
  if (c >= CP) return;
  float s = 0.f;
  const float* p = W + (size_t)b * 256 * CP + c;
  for (int r = 0; r < 256; ++r) s += p[(size_t)r * CP];
  wsump[b * CP + c] = s;
}

__global__ __launch_bounds__(128) void k_sumb(const float* __restrict__ wsump,
        const float* __restrict__ supcnt, float* __restrict__ sumb) {
  int c = threadIdx.x;
  if (c >= CP) return;
  float s = supcnt[c];
  for (int b = 0; b < NQ / 256; ++b) s += wsump[b * CP + c];
  sumb[c] = s;
}

__global__ __launch_bounds__(256) void k_upd(const float* __restrict__ supsum,
        const float* __restrict__ part, const float* __restrict__ sumb,
        float* __restrict__ cent) {
  int c = blockIdx.x;
  int d = blockIdx.y * 256 + threadIdx.x;
  float s = supsum[(size_t)c * D + d];
  for (int kc = 0; kc < KC; ++kc) s += part[((size_t)kc * CP + c) * D + d];
  cent[(size_t)c * D + d] = (c < C) ? s / sumb[c] : 0.f;
}

// ---------------- launch ----------------

extern "C" void kernel_launch(void* const* d_in, const int* in_sizes, int n_in,
                              void* d_out, int out_size, void* d_ws, size_t ws_size,
                              hipStream_t stream) {
  const float* sx = (const float*)d_in[0];
  const int*   sy = (const int*)d_in[1];
  const float* qx = (const float*)d_in[2];
  const int*   qy = (const int*)d_in[3];

  // ---- fast-path workspace layout ----
  char* base = (char*)d_ws;
  size_t o = 0;
  auto take = [&](size_t bytes) { size_t r = o; o += (bytes + 511) & ~(size_t)511; return r; };
  float* mean   = (float*)(base + take(4096));
  float* invs   = (float*)(base + take(4096));
  float* invq   = (float*)(base + take((size_t)NQ * 4));
  float* supsum = (float*)(base + take((size_t)CP * D * 4));
  float* supcnt = (float*)(base + take(512));
  float* c2A    = (float*)(base + take(512));
  float* c2B    = (float*)(base + take(512));
  float* sumb   = (float*)(base + take(512));
  float* wsump  = (float*)(base + take((size_t)(NQ / 128) * CP * 4));
  int*   corr   = (int*)(base + take(512));
  u16* chiA = (u16*)(base + take((size_t)CP * D * 2));
  u16* cloA = (u16*)(base + take((size_t)CP * D * 2));
  u16* chiB = (u16*)(base + take((size_t)CP * D * 2));
  u16* cloB = (u16*)(base + take((size_t)CP * D * 2));
  u16* Wthi = (u16*)(base + take((size_t)CP * NQ * 2));
  u16* Wtlo = (u16*)(base + take((size_t)CP * NQ * 2));
  float* part = (float*)(base + take((size_t)KC * CP * D * 4));
  u16* qhi  = (u16*)(base + take((size_t)NQ * D * 2));
  u16* qlo  = (u16*)(base + take((size_t)NQ * D * 2));
  u16* qthi = (u16*)(base + take((size_t)NQ * D * 2));
  u16* qtlo = (u16*)(base + take((size_t)NQ * D * 2));
  size_t fast_need = o;

  if (ws_size >= fast_need) {
    k_mean<<<dim3(D / 256), 256, 0, stream>>>(sx, mean);
    k_invn<<<dim3(NS), 256, 0, stream>>>(sx, mean, invs);
    k_invn<<<dim3(NQ), 256, 0, stream>>>(qx, mean, invq);
    k_supsum<<<dim3(CP), 256, 0, stream>>>(sx, sy, mean, invs, supsum, supcnt);
    k_updm<<<dim3(CP), 256, 0, stream>>>(supsum, part, supcnt, chiA, cloA, c2A, 0);
    k_qsplit<<<dim3(NQ / 64, D / 64), 256, 0, stream>>>(qx, mean, invq, qhi, qlo, qthi, qtlo);

    u16 *chc = chiA, *clc = cloA, *chn = chiB, *cln = cloB;
    float *c2c = c2A, *c2n = c2B;
    for (int it = 0; it < NITER; ++it) {
      k_logits<<<dim3(NQ / 128), 256, 0, stream>>>(qhi, qlo, chc, clc, c2c,
                                                   Wthi, Wtlo, wsump, nullptr, nullptr, 0);
      k_sumbm<<<dim3(1), 128, 0, stream>>>(wsump, supcnt, sumb);
      k_wqm<<<dim3(D / 128, KC), 256, 0, stream>>>(Wthi, Wtlo, qthi, qtlo, part);
      k_updm<<<dim3(CP), 256, 0, stream>>>(supsum, part, sumb, chn, cln, c2n, KC);
      u16* tu;
      tu = chc; chc = chn; chn = tu;
      tu = clc; clc = cln; cln = tu;
      float* tf = c2c; c2c = c2n; c2n = tf;
    }
    k_zero<<<1, 64, 0, stream>>>(corr);
    k_logits<<<dim3(NQ / 128), 256, 0, stream>>>(qhi, qlo, chc, clc, c2c,
                                                 nullptr, nullptr, nullptr, qy, corr, 1);
    k_out<<<1, 64, 0, stream>>>(corr, (float*)d_out);
    return;
  }

  // ---- fallback: round-1 fp32 path ----
  float* ws = (float*)d_ws;
  float* mean1   = ws;
  float* invs1   = mean1 + 1024;
  float* supsum1 = invs1 + 1024;
  float* supcnt1 = supsum1 + (size_t)CP * D;
  float* cA      = supcnt1 + 128;
  float* cB      = cA + (size_t)CP * D;
  float* c21     = cB + (size_t)CP * D;
  float* invq1   = c21 + 128;
  float* W1      = invq1 + NQ;
  float* part1   = W1 + (size_t)NQ * CP;
  float* wsump1  = part1 + (size_t)KC * CP * D;
  float* sumb1   = wsump1 + (size_t)(NQ / 256) * CP;
  int*   corr1   = (int*)(sumb1 + 128);
  size_t needed = (size_t)((sumb1 + 128 + 1024) - ws) * sizeof(float);
  if (ws_size < needed) {
    k_zero<<<1, 64, 0, stream>>>((int*)d_out);
    return;
  }

  k_mean<<<dim3(D / 256), 256, 0, stream>>>(sx, mean1);
  k_invn<<<dim3(NS), 256, 0, stream>>>(sx, mean1, invs1);
  k_invn<<<dim3(NQ), 256, 0, stream>>>(qx, mean1, invq1);
  k_supsum<<<dim3(CP), 256, 0, stream>>>(sx, sy, mean1, invs1, supsum1, supcnt1);
  k_cent0<<<dim3(CP, D / 256), 256, 0, stream>>>(supsum1, supcnt1, cA);
  k_c2<<<dim3(CP), 256, 0, stream>>>(cA, c21);

  float* cur = cA;
  float* nxt = cB;
  for (int it = 0; it < NITER; ++it) {
    k_qc<false><<<dim3(NQ / 128), 256, 0, stream>>>(qx, mean1, invq1, cur, c21, W1, nullptr, nullptr);
    k_wsum<<<dim3(NQ / 256), 128, 0, stream>>>(W1, wsump1);
    k_sumb<<<dim3(1), 128, 0, stream>>>(wsump1, supcnt1, sumb1);
    k_wq<<<dim3(D / 128, KC), 256, 0, stream>>>(W1, qx, mean1, invq1, part1);
    k_upd<<<dim3(CP, D / 256), 256, 0, stream>>>(supsum1, part1, sumb1, nxt);
    k_c2<<<dim3(CP), 256, 0, stream>>>(nxt, c21);
    float* tmp = cur; cur = nxt; nxt = tmp;
  }

  k_zero<<<1, 64, 0, stream>>>(corr1);
  k_qc<true><<<dim3(NQ / 128), 256, 0, stream>>>(qx, mean1, invq1, cur, c21, W1, qy, corr1);
  k_out<<<1, 64, 0, stream>>>(corr1, (float*)d_out);
}

// Round 3
// 3793.547 us; speedup vs baseline: 2.6321x; 1.1731x over previous
//
#include <hip/hip_runtime.h>
#include <math.h>

#define NS 1000
#define NQ 131072
#define D  1024
#define C  100
#define CP 112          // padded class count (16*7)
#define BETA 5.0f
#define NITER 10
#define KC 64           // split-K chunks for W^T q
#define KROWS (NQ/KC)   // 2048

typedef float f32x4 __attribute__((ext_vector_type(4)));
typedef short s16x8 __attribute__((ext_vector_type(8)));
typedef unsigned short u16;

__device__ __forceinline__ u16 f2bf(float x) {
  union { float f; unsigned u; } v; v.f = x;
  unsigned r = v.u + 0x7fffu + ((v.u >> 16) & 1u);
  return (u16)(r >> 16);
}
__device__ __forceinline__ float bf2f(u16 h) {
  union { unsigned u; float f; } v; v.u = ((unsigned)h) << 16; return v.f;
}
__device__ __forceinline__ void gld16(const u16* g, u16* l) {
  __builtin_amdgcn_global_load_lds(
      (const __attribute__((address_space(1))) void*)g,
      (__attribute__((address_space(3))) void*)l, 16, 0, 0);
}
// planes are [rows][32 u16]; granule (16B) XOR-swizzled by row&3 (both sides)
__device__ __forceinline__ s16x8 frag32(const u16* plane, int row, int kb) {
  int s = kb ^ (row & 3);
  return *(const s16x8*)(plane + row * 32 + s * 8);
}
__device__ __forceinline__ f32x4 mfma16(s16x8 a, s16x8 b, f32x4 c) {
  return __builtin_amdgcn_mfma_f32_16x16x32_bf16(a, b, c, 0, 0, 0);
}

// ---------------- prep kernels ----------------

__global__ __launch_bounds__(256) void k_mean(const float* __restrict__ sx,
                                              float* __restrict__ mean) {
  int d = blockIdx.x * 256 + threadIdx.x;
  float a = 0.f;
  for (int r = 0; r < NS; ++r) a += sx[(size_t)r * D + d];
  mean[d] = a / (float)NS;
}

__global__ __launch_bounds__(256) void k_invn(const float* __restrict__ x,
                                              const float* __restrict__ mean,
                                              float* __restrict__ invn) {
  int r = blockIdx.x;
  int t = threadIdx.x;
  float4 v = ((const float4*)(x + (size_t)r * D))[t];
  float4 m = ((const float4*)mean)[t];
  float a = v.x - m.x, b = v.y - m.y, c = v.z - m.z, d = v.w - m.w;
  float s = a * a + b * b + c * c + d * d;
#pragma unroll
  for (int off = 1; off < 64; off <<= 1) s += __shfl_xor(s, off);
  __shared__ float ws[4];
  if ((t & 63) == 0) ws[t >> 6] = s;
  __syncthreads();
  if (t == 0) invn[r] = 1.0f / sqrtf(ws[0] + ws[1] + ws[2] + ws[3]);
}

__global__ __launch_bounds__(256) void k_supsum(const float* __restrict__ sx,
        const int* __restrict__ sy, const float* __restrict__ mean,
        const float* __restrict__ invs, float* __restrict__ supsum,
        float* __restrict__ supcnt) {
  int c = blockIdx.x;
  int t = threadIdx.x;
  float a0 = 0.f, a1 = 0.f, a2 = 0.f, a3 = 0.f;
  int cnt = 0;
  if (c < C) {
    for (int r = 0; r < NS; ++r) {
      if (sy[r] == c) {
        ++cnt;
        float inv = invs[r];
        a0 += (sx[(size_t)r * D + t      ] - mean[t      ]) * inv;
        a1 += (sx[(size_t)r * D + t + 256] - mean[t + 256]) * inv;
        a2 += (sx[(size_t)r * D + t + 512] - mean[t + 512]) * inv;
        a3 += (sx[(size_t)r * D + t + 768] - mean[t + 768]) * inv;
      }
    }
  }
  supsum[(size_t)c * D + t      ] = a0;
  supsum[(size_t)c * D + t + 256] = a1;
  supsum[(size_t)c * D + t + 512] = a2;
  supsum[(size_t)c * D + t + 768] = a3;
  if (t == 0) supcnt[c] = (float)cnt;
}

__global__ void k_zero(int* __restrict__ corr) {
  if (threadIdx.x == 0) corr[0] = 0;
}

__global__ void k_out(const int* __restrict__ corr, float* __restrict__ out) {
  if (threadIdx.x == 0) out[0] = (float)corr[0] * (1.0f / (float)NQ);
}

// normalize q, split bf16; write qhi/qlo [q][D] + qthi [d][NQ] (hi only)
__global__ __launch_bounds__(256) void k_qsplit(const float* __restrict__ qx,
        const float* __restrict__ mean, const float* __restrict__ invq,
        u16* __restrict__ qhi, u16* __restrict__ qlo, u16* __restrict__ qthi) {
  __shared__ u16 Lh[64][70];
  __shared__ float mloc[64], iloc[64];
  int t = threadIdx.x;
  int q0 = blockIdx.x * 64, d0 = blockIdx.y * 64;
  if (t < 16) ((float4*)mloc)[t] = ((const float4*)(mean + d0))[t];
  else if (t < 32) ((float4*)iloc)[t - 16] = ((const float4*)(invq + q0))[t - 16];
  __syncthreads();
  int r = t >> 2, c0 = (t & 3) * 16;
  float inv = iloc[r];
  const float* src = qx + (size_t)(q0 + r) * D + d0 + c0;
  union { u16 s[16]; uint4 q[2]; } H, L;
#pragma unroll
  for (int j = 0; j < 16; j += 4) {
    float4 v = *(const float4*)(src + j);
    float xs[4] = {v.x, v.y, v.z, v.w};
#pragma unroll
    for (int u = 0; u < 4; ++u) {
      float x = (xs[u] - mloc[c0 + j + u]) * inv;
      u16 h = f2bf(x);
      H.s[j + u] = h;
      L.s[j + u] = f2bf(x - bf2f(h));
    }
  }
#pragma unroll
  for (int j = 0; j < 16; j += 2)   // ushort2 stores: 4B-aligned for stride 70
    *(ushort2*)&Lh[r][c0 + j] = make_ushort2(H.s[j], H.s[j + 1]);
  u16* dh = qhi + (size_t)(q0 + r) * D + d0 + c0;
  u16* dl = qlo + (size_t)(q0 + r) * D + d0 + c0;
  *(uint4*)(dh) = H.q[0]; *(uint4*)(dh + 8) = H.q[1];
  *(uint4*)(dl) = L.q[0]; *(uint4*)(dl + 8) = L.q[1];
  __syncthreads();
  // transpose 4x4 sub-tiles: thread (tq,td) reads rows q=tq*4..+3, cols d=td*4..+3
  int tq4 = (t & 15) * 4, td4 = (t >> 4) * 4;
  u16 a[4][4];
#pragma unroll
  for (int i = 0; i < 4; ++i) {
    ushort2 p0 = *(const ushort2*)&Lh[tq4 + i][td4];
    ushort2 p1 = *(const ushort2*)&Lh[tq4 + i][td4 + 2];
    a[i][0] = p0.x; a[i][1] = p0.y; a[i][2] = p1.x; a[i][3] = p1.y;
  }
#pragma unroll
  for (int j = 0; j < 4; ++j)
    *(ushort4*)(qthi + (size_t)(d0 + td4 + j) * NQ + q0 + tq4) =
        make_ushort4(a[0][j], a[1][j], a[2][j], a[3][j]);
}

// centroid update (nparts=0: init) -> bf16 hi/lo planes + |c|^2 (consistent fp32)
__global__ __launch_bounds__(256) void k_updm(const float* __restrict__ supsum,
        const float* __restrict__ part, const float* __restrict__ denom,
        u16* __restrict__ chi, u16* __restrict__ clo, float* __restrict__ c2,
        int nparts) {
  int c = blockIdx.x, t = threadIdx.x;
  float den = denom[c];
  float ss = 0.f;
  float vals[4];
#pragma unroll
  for (int j = 0; j < 4; ++j) {
    int d = t + j * 256;
    float s = supsum[(size_t)c * D + d];
    for (int kc = 0; kc < nparts; ++kc) s += part[((size_t)kc * CP + c) * D + d];
    float v = (c < C) ? s / den : 0.f;
    vals[j] = v; ss += v * v;
  }
#pragma unroll
  for (int j = 0; j < 4; ++j) {
    int d = t + j * 256;
    u16 h = f2bf(vals[j]);
    chi[(size_t)c * D + d] = h;
    clo[(size_t)c * D + d] = f2bf(vals[j] - bf2f(h));
  }
#pragma unroll
  for (int off = 1; off < 64; off <<= 1) ss += __shfl_xor(ss, off);
  __shared__ float red[4];
  if ((t & 63) == 0) red[t >> 6] = ss;
  __syncthreads();
  if (t == 0) c2[c] = (c < C) ? (red[0] + red[1] + red[2] + red[3]) : 1e30f;
}

// ---------------- GEMM1: logits + softmax -> Wt(bf16) + col sums; FINAL: argmax ----------------

template<int FINAL>
__global__ __launch_bounds__(256) void k_logits(
    const u16* __restrict__ qhi, const u16* __restrict__ qlo,
    const u16* __restrict__ chi, const u16* __restrict__ clo,
    const float* __restrict__ c2,
    u16* __restrict__ Wthi, float* __restrict__ wsump,
    const int* __restrict__ qy, int* __restrict__ corr) {
  // per buffer (u16): Ah[128*32]@0, Al@4096, Bh[112*32]@8192, Bl@11776 -> 15360
  __shared__ __align__(16) u16 sm[2][15360];
  __shared__ float wred[4][CP];
  int t = threadIdx.x, w = t >> 6, l = t & 63;
  int q0 = blockIdx.x * 128;
  int rr = l >> 2;
  int sg = ((l & 3) ^ (rr & 3)) * 8;   // pre-swizzled source granule (u16 offset)

  f32x4 acc[2][7];
#pragma unroll
  for (int mf = 0; mf < 2; ++mf)
#pragma unroll
    for (int nf = 0; nf < 7; ++nf) acc[mf][nf] = (f32x4){0.f, 0.f, 0.f, 0.f};

  auto stage = [&](int p, int ks) {   // per-wave: w<3 -> 8 calls, w==3 -> 6
    int k0 = ks * 32;
    u16* b = sm[p];
#pragma unroll
    for (int i = w * 2; i < w * 2 + 2; ++i) {
      gld16(qhi + (size_t)(q0 + i * 16 + rr) * D + k0 + sg, b + i * 512);
      gld16(qlo + (size_t)(q0 + i * 16 + rr) * D + k0 + sg, b + 4096 + i * 512);
    }
    for (int i = w; i < 7; i += 4) {
      gld16(chi + (size_t)(i * 16 + rr) * D + k0 + sg, b + 8192 + i * 512);
      gld16(clo + (size_t)(i * 16 + rr) * D + k0 + sg, b + 11776 + i * 512);
    }
  };

  stage(0, 0);
  for (int ks = 0; ks < 32; ++ks) {
    int cur = ks & 1;
    if (ks < 31) {
      stage(cur ^ 1, ks + 1);
      if (w < 3) asm volatile("s_waitcnt vmcnt(8)" ::: "memory");
      else       asm volatile("s_waitcnt vmcnt(6)" ::: "memory");
    } else {
      asm volatile("s_waitcnt vmcnt(0)" ::: "memory");
    }
    __builtin_amdgcn_s_barrier();        // cur loads visible to all waves
    const u16* b = sm[cur];
    int kb = l >> 4;
    s16x8 ah[2], al[2];
#pragma unroll
    for (int mf = 0; mf < 2; ++mf) {
      int row = w * 32 + mf * 16 + (l & 15);
      ah[mf] = frag32(b, row, kb);
      al[mf] = frag32(b + 4096, row, kb);
    }
#pragma unroll
    for (int nf = 0; nf < 7; ++nf) {
      int row = nf * 16 + (l & 15);
      s16x8 bh = frag32(b + 8192, row, kb);
      s16x8 bl = frag32(b + 11776, row, kb);
#pragma unroll
      for (int mf = 0; mf < 2; ++mf) {
        f32x4 a = acc[mf][nf];
        a = mfma16(al[mf], bh, a);       // lo*hi
        a = mfma16(ah[mf], bl, a);       // hi*lo
        a = mfma16(ah[mf], bh, a);       // hi*hi   (lo*lo dropped)
        acc[mf][nf] = a;
      }
    }
    __builtin_amdgcn_s_barrier();        // done reading cur before it's restaged
    asm volatile("" ::: "memory");
  }

  float c2v[7];
#pragma unroll
  for (int nf = 0; nf < 7; ++nf) c2v[nf] = c2[nf * 16 + (l & 15)];

  if (!FINAL) {
    float wcol[7];
#pragma unroll
    for (int nf = 0; nf < 7; ++nf) wcol[nf] = 0.f;
    u16* Wsh = sm[0];   // [112][128] u16, granule-swizzled by class low bits
#pragma unroll
    for (int mf = 0; mf < 2; ++mf)
#pragma unroll
      for (int r = 0; r < 4; ++r) {
        float Lg[7], mx = -INFINITY;
#pragma unroll
        for (int nf = 0; nf < 7; ++nf) {
          Lg[nf] = 2.f * acc[mf][nf][r] - c2v[nf];
          mx = fmaxf(mx, Lg[nf]);
        }
#pragma unroll
        for (int off = 1; off < 16; off <<= 1) mx = fmaxf(mx, __shfl_xor(mx, off));
        float e[7], s = 0.f;
#pragma unroll
        for (int nf = 0; nf < 7; ++nf) { e[nf] = expf(BETA * (Lg[nf] - mx)); s += e[nf]; }
#pragma unroll
        for (int off = 1; off < 16; off <<= 1) s += __shfl_xor(s, off);
        float is = 1.f / s;
        int qi = w * 32 + mf * 16 + (l >> 4) * 4 + r;
        int qs = qi ^ ((l & 15) << 3);
#pragma unroll
        for (int nf = 0; nf < 7; ++nf) {
          float wv = e[nf] * is;
          wcol[nf] += wv;
          Wsh[(nf * 16 + (l & 15)) * 128 + qs] = f2bf(wv);
        }
      }
#pragma unroll
    for (int off = 16; off < 64; off <<= 1)
#pragma unroll
      for (int nf = 0; nf < 7; ++nf) wcol[nf] += __shfl_xor(wcol[nf], off);
    if (l < 16)
#pragma unroll
      for (int nf = 0; nf < 7; ++nf) wred[w][nf * 16 + l] = wcol[nf];
    __syncthreads();
    for (int idx = t; idx < 1792; idx += 256) {
      int c = idx >> 4, p = idx & 15;
      int ps = p ^ (c & 15);
      *(uint4*)(Wthi + (size_t)c * NQ + q0 + p * 8) = *(const uint4*)(Wsh + c * 128 + ps * 8);
    }
    if (t < CP) wsump[(size_t)blockIdx.x * CP + t] =
        wred[0][t] + wred[1][t] + wred[2][t] + wred[3][t];
  } else {
    int cnt = 0;
#pragma unroll
    for (int mf = 0; mf < 2; ++mf)
#pragma unroll
      for (int r = 0; r < 4; ++r) {
        float bv = -INFINITY; int bi = 0x7fffffff;
#pragma unroll
        for (int nf = 0; nf < 7; ++nf) {
          float Lg = 2.f * acc[mf][nf][r] - c2v[nf];
          int cc = nf * 16 + (l & 15);
          if (Lg > bv || (Lg == bv && cc < bi)) { bv = Lg; bi = cc; }
        }
#pragma unroll
        for (int off = 1; off < 16; off <<= 1) {
          float ov = __shfl_xor(bv, off); int oi = __shfl_xor(bi, off);
          if (ov > bv || (ov == bv && oi < bi)) { bv = ov; bi = oi; }
        }
        if ((l & 15) == 0) {
          int qi = w * 32 + mf * 16 + (l >> 4) * 4 + r;
          cnt += (bi == qy[q0 + qi]) ? 1 : 0;
        }
      }
    if ((l & 15) == 0) atomicAdd(corr, cnt);
  }
}

// ---------------- GEMM2: part[ck] = Wt[:,chunk] @ qt[:,chunk]^T ----------------

__global__ __launch_bounds__(256) void k_wqm(
    const u16* __restrict__ Wthi, const u16* __restrict__ qthi,
    float* __restrict__ part) {
  // per buffer (u16): Wh[112*32]@0, Qt[128*32]@3584 -> 7680
  __shared__ __align__(16) u16 sm[2][7680];
  int t = threadIdx.x, w = t >> 6, l = t & 63;
  int d0 = blockIdx.x * 128;
  size_t qb = (size_t)blockIdx.y * KROWS;
  int rr = l >> 2;
  int sg = ((l & 3) ^ (rr & 3)) * 8;

  f32x4 acc[7][2];
#pragma unroll
  for (int mf = 0; mf < 7; ++mf)
#pragma unroll
    for (int nf = 0; nf < 2; ++nf) acc[mf][nf] = (f32x4){0.f, 0.f, 0.f, 0.f};

  auto stage = [&](int p, int ks) {   // per-wave: w<3 -> 4 calls, w==3 -> 3
    size_t k0 = qb + (size_t)ks * 32;
    u16* b = sm[p];
    for (int i = w; i < 7; i += 4)
      gld16(Wthi + (size_t)(i * 16 + rr) * NQ + k0 + sg, b + i * 512);
#pragma unroll
    for (int i = w * 2; i < w * 2 + 2; ++i)
      gld16(qthi + (size_t)(d0 + i * 16 + rr) * NQ + k0 + sg, b + 3584 + i * 512);
  };

  stage(0, 0);
  for (int ks = 0; ks < KROWS / 32; ++ks) {
    int cur = ks & 1;
    if (ks < KROWS / 32 - 1) {
      stage(cur ^ 1, ks + 1);
      if (w < 3) asm volatile("s_waitcnt vmcnt(4)" ::: "memory");
      else       asm volatile("s_waitcnt vmcnt(3)" ::: "memory");
    } else {
      asm volatile("s_waitcnt vmcnt(0)" ::: "memory");
    }
    __builtin_amdgcn_s_barrier();
    const u16* b = sm[cur];
    int kb = l >> 4;
    s16x8 bq[2];
#pragma unroll
    for (int nf = 0; nf < 2; ++nf)
      bq[nf] = frag32(b + 3584, w * 32 + nf * 16 + (l & 15), kb);
#pragma unroll
    for (int mf = 0; mf < 7; ++mf) {
      s16x8 aw = frag32(b, mf * 16 + (l & 15), kb);
      acc[mf][0] = mfma16(aw, bq[0], acc[mf][0]);
      acc[mf][1] = mfma16(aw, bq[1], acc[mf][1]);
    }
    __builtin_amdgcn_s_barrier();
    asm volatile("" ::: "memory");
  }
#pragma unroll
  for (int mf = 0; mf < 7; ++mf)
#pragma unroll
    for (int nf = 0; nf < 2; ++nf)
#pragma unroll
      for (int r = 0; r < 4; ++r) {
        int c = mf * 16 + (l >> 4) * 4 + r;
        int dg = d0 + w * 32 + nf * 16 + (l & 15);
        part[((size_t)blockIdx.y * CP + c) * D + dg] = acc[mf][nf][r];
      }
}

__global__ __launch_bounds__(128) void k_sumbm(const float* __restrict__ wsump,
        const float* __restrict__ supcnt, float* __restrict__ sumb) {
  int c = threadIdx.x;
  if (c >= CP) return;
  float s = supcnt[c];
  for (int b = 0; b < NQ / 128; ++b) s += wsump[(size_t)b * CP + c];
  sumb[c] = s;
}

// ---------------- launch ----------------

extern "C" void kernel_launch(void* const* d_in, const int* in_sizes, int n_in,
                              void* d_out, int out_size, void* d_ws, size_t ws_size,
                              hipStream_t stream) {
  const float* sx = (const float*)d_in[0];
  const int*   sy = (const int*)d_in[1];
  const float* qx = (const float*)d_in[2];
  const int*   qy = (const int*)d_in[3];

  char* base = (char*)d_ws;
  size_t o = 0;
  auto take = [&](size_t bytes) { size_t r = o; o += (bytes + 511) & ~(size_t)511; return r; };
  float* mean   = (float*)(base + take(4096));
  float* invs   = (float*)(base + take(4096));
  float* invq   = (float*)(base + take((size_t)NQ * 4));
  float* supsum = (float*)(base + take((size_t)CP * D * 4));
  float* supcnt = (float*)(base + take(512));
  float* c2A    = (float*)(base + take(512));
  float* c2B    = (float*)(base + take(512));
  float* sumb   = (float*)(base + take(512));
  float* wsump  = (float*)(base + take((size_t)(NQ / 128) * CP * 4));
  int*   corr   = (int*)(base + take(512));
  u16* chiA = (u16*)(base + take((size_t)CP * D * 2));
  u16* cloA = (u16*)(base + take((size_t)CP * D * 2));
  u16* chiB = (u16*)(base + take((size_t)CP * D * 2));
  u16* cloB = (u16*)(base + take((size_t)CP * D * 2));
  u16* Wthi = (u16*)(base + take((size_t)CP * NQ * 2));
  float* part = (float*)(base + take((size_t)KC * CP * D * 4));
  u16* qhi  = (u16*)(base + take((size_t)NQ * D * 2));
  u16* qlo  = (u16*)(base + take((size_t)NQ * D * 2));
  u16* qthi = (u16*)(base + take((size_t)NQ * D * 2));
  size_t fast_need = o;

  if (ws_size < fast_need) {   // visible sentinel; harness ws has been ~>1.4GB
    k_zero<<<1, 64, 0, stream>>>((int*)d_out);
    return;
  }

  k_mean<<<dim3(D / 256), 256, 0, stream>>>(sx, mean);
  k_invn<<<dim3(NS), 256, 0, stream>>>(sx, mean, invs);
  k_invn<<<dim3(NQ), 256, 0, stream>>>(qx, mean, invq);
  k_supsum<<<dim3(CP), 256, 0, stream>>>(sx, sy, mean, invs, supsum, supcnt);
  k_updm<<<dim3(CP), 256, 0, stream>>>(supsum, part, supcnt, chiA, cloA, c2A, 0);
  k_qsplit<<<dim3(NQ / 64, D / 64), 256, 0, stream>>>(qx, mean, invq, qhi, qlo, qthi);

  u16 *chc = chiA, *clc = cloA, *chn = chiB, *cln = cloB;
  float *c2c = c2A, *c2n = c2B;
  for (int it = 0; it < NITER; ++it) {
    k_logits<0><<<dim3(NQ / 128), 256, 0, stream>>>(qhi, qlo, chc, clc, c2c,
                                                    Wthi, wsump, nullptr, nullptr);
    k_sumbm<<<dim3(1), 128, 0, stream>>>(wsump, supcnt, sumb);
    k_wqm<<<dim3(D / 128, KC), 256, 0, stream>>>(Wthi, qthi, part);
    k_updm<<<dim3(CP), 256, 0, stream>>>(supsum, part, sumb, chn, cln, c2n, KC);
    u16* tu;
    tu = chc; chc = chn; chn = tu;
    tu = clc; clc = cln; cln = tu;
    float* tf = c2c; c2c = c2n; c2n = tf;
  }
  k_zero<<<1, 64, 0, stream>>>(corr);
  k_logits<1><<<dim3(NQ / 128), 256, 0, stream>>>(qhi, qlo, chc, clc, c2c,
                                                  nullptr, nullptr, qy, corr);
  k_out<<<1, 64, 0, stream>>>(corr, (float*)d_out);
}